// Round 1
// baseline (1069.456 us; speedup 1.0000x reference)
//
#include <hip/hip_runtime.h>
#include <math.h>

// ---------------------------------------------------------------------------
// WaveRNN fused kernel: conv1(1->4,k31,s4,p15) -> relu -> conv2(4->8,k15,s4,p7)
// -> relu -> conv3(8->16,k7,s4,p3) -> relu -> mean -> GRU cell (H=32) -> proj.
// One 256-thread block per batch item. All intermediates in LDS.
//
// LDS layouts (data offsets chosen so conv reads are float4-aligned):
//   x0s[2032]  : pad16 | 2000 samples | pad16        (conv1 reads idx 4p..4p+31)
//   y1s[4*512] : per ch: pad7 | 500 | pad5           (conv2 reads idx 4p..4p+15)
//   y2s[8*132] : per ch: pad3 | 125 | pad4           (conv3 reads idx 4p..4p+7)
// Conv weight indices are compile-time (templates + wave-uniform branches) so
// the compiler emits s_load (scalar, K$-hot) instead of per-lane loads.
// ---------------------------------------------------------------------------

template<int CBASE>
__device__ __forceinline__ void conv2_group(const float* __restrict__ y1s,
                                            float* __restrict__ y2s,
                                            const float* __restrict__ w2,
                                            const float* __restrict__ b2,
                                            int p)
{
    float acc[4] = {b2[CBASE + 0], b2[CBASE + 1], b2[CBASE + 2], b2[CBASE + 3]};
#pragma unroll
    for (int ci = 0; ci < 4; ++ci) {
        float xin[16];
        const float4* src = (const float4*)(y1s + ci * 512);
#pragma unroll
        for (int j = 0; j < 4; ++j) {
            float4 q = src[p + j];
            xin[4 * j + 0] = q.x; xin[4 * j + 1] = q.y;
            xin[4 * j + 2] = q.z; xin[4 * j + 3] = q.w;
        }
#pragma unroll
        for (int k = 0; k < 15; ++k) {
#pragma unroll
            for (int c = 0; c < 4; ++c)
                acc[c] += xin[k] * w2[((CBASE + c) * 4 + ci) * 15 + k];
        }
    }
#pragma unroll
    for (int c = 0; c < 4; ++c)
        y2s[(CBASE + c) * 132 + 3 + p] = fmaxf(acc[c], 0.0f);
}

template<int C4, int CIBASE>
__device__ __forceinline__ void conv3_partial(const float* __restrict__ y2s,
                                              const float* __restrict__ w3,
                                              float acc[4], int p)
{
#pragma unroll
    for (int i = 0; i < 4; ++i) {
        const int ci = CIBASE + i;
        float xin[8];
        const float4* src = (const float4*)(y2s + ci * 132);
        float4 q0 = src[p];
        float4 q1 = src[p + 1];
        xin[0] = q0.x; xin[1] = q0.y; xin[2] = q0.z; xin[3] = q0.w;
        xin[4] = q1.x; xin[5] = q1.y; xin[6] = q1.z; xin[7] = q1.w;
#pragma unroll
        for (int k = 0; k < 7; ++k) {
#pragma unroll
            for (int c = 0; c < 4; ++c)
                acc[c] += xin[k] * w3[((C4 * 4 + c) * 8 + ci) * 7 + k];
        }
    }
}

__global__ void __launch_bounds__(256)
wavernn_fused(const float* __restrict__ past,      // (B,2000)
              const float* __restrict__ velocity,  // (B,)
              const float* __restrict__ log_pitch, // (B,)
              const float* __restrict__ time_in,   // (B,)
              const float* __restrict__ hidden,    // (B,32)
              const float* __restrict__ w1, const float* __restrict__ b1,
              const float* __restrict__ w2, const float* __restrict__ b2,
              const float* __restrict__ w3, const float* __restrict__ b3,
              const float* __restrict__ w_ih, const float* __restrict__ w_hh,
              const float* __restrict__ b_ih, const float* __restrict__ b_hh,
              const float* __restrict__ w_proj, const float* __restrict__ b_proj,
              float* __restrict__ out, int B)
{
    __shared__ __align__(16) float x0s[2032];
    __shared__ __align__(16) float y1s[4 * 512];
    __shared__ __align__(16) float y2s[8 * 132];
    __shared__ float rnn[20];   // [0..15]=ctx, 16=vel, 17=log_pitch, 18=time
    __shared__ float gis[96];
    __shared__ float ghs[96];
    __shared__ float hs[32];

    const int t = threadIdx.x;
    const int b = blockIdx.x;

    // ---------------- Phase 0: stage inputs, zero pads ----------------
    {
        const float4* xrow = (const float4*)(past + (size_t)b * 2000);
        float4* xdst = (float4*)(x0s + 16);  // 16 floats = 64B aligned
        for (int i = t; i < 500; i += 256)
            xdst[i] = xrow[i];

        if (t < 16) { x0s[t] = 0.0f; x0s[2016 + t] = 0.0f; }
        if (t < 48) {                       // y1 pads: 7 left + 5 right per ch
            int c = t / 12, idx = t % 12;
            y1s[c * 512 + (idx < 7 ? idx : 500 + idx)] = 0.0f;
        }
        if (t < 56) {                       // y2 pads: 3 left + 4 right per ch
            int ci = t / 7, idx = t % 7;
            y2s[ci * 132 + (idx < 3 ? idx : 125 + idx)] = 0.0f;
        }
        if (t < 32) hs[t] = hidden[(size_t)b * 32 + t];
        if (t == 0) rnn[16] = velocity[b];
        if (t == 1) rnn[17] = log_pitch[b];
        if (t == 2) rnn[18] = time_in[b];
    }
    __syncthreads();

    // ---------------- conv1: 1->4ch, k=31, s=4 ----------------
    // raw input idx = 4p - 15 + k; data offset 16 => LDS idx = 4p + 1 + k
    for (int p = t; p < 500; p += 256) {
        float xin[32];
        const float4* src = (const float4*)x0s;
#pragma unroll
        for (int j = 0; j < 8; ++j) {
            float4 q = src[p + j];
            xin[4 * j + 0] = q.x; xin[4 * j + 1] = q.y;
            xin[4 * j + 2] = q.z; xin[4 * j + 3] = q.w;
        }
        float a0 = b1[0], a1 = b1[1], a2 = b1[2], a3 = b1[3];
#pragma unroll
        for (int k = 0; k < 31; ++k) {
            float xv = xin[k + 1];
            a0 += xv * w1[k];
            a1 += xv * w1[31 + k];
            a2 += xv * w1[62 + k];
            a3 += xv * w1[93 + k];
        }
        y1s[7 + p]           = fmaxf(a0, 0.0f);
        y1s[512 + 7 + p]     = fmaxf(a1, 0.0f);
        y1s[1024 + 7 + p]    = fmaxf(a2, 0.0f);
        y1s[1536 + 7 + p]    = fmaxf(a3, 0.0f);
    }
    __syncthreads();

    // ---------------- conv2: 4->8ch, k=15, s=4 ----------------
    // threads 0..127 -> out ch 0..3, threads 128..255 -> out ch 4..7
    {
        int p = t & 127;
        if (p < 125) {
            if (t < 128) conv2_group<0>(y1s, y2s, w2, b2, p);
            else         conv2_group<4>(y1s, y2s, w2, b2, p);
        }
    }
    __syncthreads();

    // ---------------- conv3: 8->16ch, k=7, s=4 + relu + mean ----------------
    // wave w (t>>6) handles out ch 4w..4w+3; halves of the wave split input ch.
    {
        const int wv  = t >> 6;
        const int cih = (t >> 5) & 1;
        const int p   = t & 31;
        float acc[4] = {0.f, 0.f, 0.f, 0.f};
        if (wv == 0) { if (cih == 0) conv3_partial<0, 0>(y2s, w3, acc, p);
                       else          conv3_partial<0, 4>(y2s, w3, acc, p); }
        else if (wv == 1) { if (cih == 0) conv3_partial<1, 0>(y2s, w3, acc, p);
                            else          conv3_partial<1, 4>(y2s, w3, acc, p); }
        else if (wv == 2) { if (cih == 0) conv3_partial<2, 0>(y2s, w3, acc, p);
                            else          conv3_partial<2, 4>(y2s, w3, acc, p); }
        else              { if (cih == 0) conv3_partial<3, 0>(y2s, w3, acc, p);
                            else          conv3_partial<3, 4>(y2s, w3, acc, p); }
#pragma unroll
        for (int c = 0; c < 4; ++c) {
            float v = acc[c] + __shfl_xor(acc[c], 32);      // combine ci halves
            v = fmaxf(v + b3[wv * 4 + c], 0.0f);            // bias + relu
            v += __shfl_xor(v, 16); v += __shfl_xor(v, 8);  // mean over 32 pos
            v += __shfl_xor(v, 4);  v += __shfl_xor(v, 2);
            v += __shfl_xor(v, 1);
            if ((t & 63) == 0) rnn[wv * 4 + c] = v * (1.0f / 32.0f);
        }
    }
    __syncthreads();

    // ---------------- GRU gates: gi (t<96), gh (96<=t<192) ----------------
    if (t < 96) {
        float a = b_ih[t];
        const float* wr = w_ih + t * 19;
#pragma unroll
        for (int j = 0; j < 19; ++j) a += rnn[j] * wr[j];
        gis[t] = a;
    } else if (t < 192) {
        int g = t - 96;
        float a = b_hh[g];
        const float* wr = w_hh + g * 32;
#pragma unroll
        for (int j = 0; j < 32; ++j) a += hs[j] * wr[j];
        ghs[g] = a;
    }
    __syncthreads();

    // ---------------- combine + projection (first wave only) ----------------
    if (t < 32) {
        const int j = t;
        float r = 1.0f / (1.0f + expf(-(gis[j] + ghs[j])));
        float z = 1.0f / (1.0f + expf(-(gis[32 + j] + ghs[32 + j])));
        float n = tanhf(gis[64 + j] + r * ghs[64 + j]);
        float nh = (1.0f - z) * n + z * hs[j];
        out[(size_t)2 * B + (size_t)b * 32 + j] = nh;   // new_hidden

        float p0 = nh * w_proj[j];
        float p1 = nh * w_proj[32 + j];
        p0 += __shfl_xor(p0, 16); p1 += __shfl_xor(p1, 16);
        p0 += __shfl_xor(p0, 8);  p1 += __shfl_xor(p1, 8);
        p0 += __shfl_xor(p0, 4);  p1 += __shfl_xor(p1, 4);
        p0 += __shfl_xor(p0, 2);  p1 += __shfl_xor(p1, 2);
        p0 += __shfl_xor(p0, 1);  p1 += __shfl_xor(p1, 1);
        if (j == 0) {
            out[b] = p0 + b_proj[0];                    // mu
            out[B + b] = expf(p1 + b_proj[1]);          // sigma
        }
    }
}

extern "C" void kernel_launch(void* const* d_in, const int* in_sizes, int n_in,
                              void* d_out, int out_size, void* d_ws, size_t ws_size,
                              hipStream_t stream)
{
    const float* past      = (const float*)d_in[0];
    const float* velocity  = (const float*)d_in[1];
    const float* log_pitch = (const float*)d_in[2];
    const float* time_in   = (const float*)d_in[3];
    const float* hidden    = (const float*)d_in[4];
    const float* w1  = (const float*)d_in[5];
    const float* b1  = (const float*)d_in[6];
    const float* w2  = (const float*)d_in[7];
    const float* b2  = (const float*)d_in[8];
    const float* w3  = (const float*)d_in[9];
    const float* b3  = (const float*)d_in[10];
    const float* wih = (const float*)d_in[11];
    const float* whh = (const float*)d_in[12];
    const float* bih = (const float*)d_in[13];
    const float* bhh = (const float*)d_in[14];
    const float* wpr = (const float*)d_in[15];
    const float* bpr = (const float*)d_in[16];

    const int B = in_sizes[0] / 2000;

    wavernn_fused<<<dim3(B), dim3(256), 0, stream>>>(
        past, velocity, log_pitch, time_in, hidden,
        w1, b1, w2, b2, w3, b3, wih, whh, bih, bhh, wpr, bpr,
        (float*)d_out, B);
}

// Round 2
// 379.604 us; speedup vs baseline: 2.8173x; 2.8173x over previous
//
#include <hip/hip_runtime.h>
#include <math.h>

// ---------------------------------------------------------------------------
// WaveRNN fused, wave-per-item: conv1(1->4,k31,s4,p15) -> relu ->
// conv2(4->8,k15,s4,p7) -> relu -> conv3(8->16,k7,s4,p3) -> relu -> mean ->
// GRU cell (H=32) -> proj.  64-thread (1-wave) blocks, one batch item each:
// no cross-wave barriers, ~9 independent items resident per CU (LDS-capped).
//
// LDS (per item, ~17.6 KB):
//   xbuf[1048]  : conv1 input staged in 2 chunks (pad16 | 1016 | pad16)
//   y1s[4*512]  : per ch: pad7 | 500 | pad5   (conv2 reads float4 [p..p+3])
//   y2s[8*132]  : per ch: pad3 | 125 | pad4   (conv3 reads float4 [p..p+1])
// All conv weight indices are compile-time -> scalar s_load path (K$-hot).
// All LDS b128 accesses are 16B/lane canonical stride (conflict-free).
// ---------------------------------------------------------------------------

__device__ __forceinline__ void conv1_pos(const float* __restrict__ xbuf,
                                          float* __restrict__ y1s,
                                          const float* __restrict__ w1,
                                          const float* __restrict__ b1,
                                          int p, int q0)
{
    const float4* src = (const float4*)xbuf;
    float xin[32];
#pragma unroll
    for (int j = 0; j < 8; ++j) {
        float4 q = src[q0 + j];
        xin[4 * j + 0] = q.x; xin[4 * j + 1] = q.y;
        xin[4 * j + 2] = q.z; xin[4 * j + 3] = q.w;
    }
    float a0 = b1[0], a1 = b1[1], a2 = b1[2], a3 = b1[3];
#pragma unroll
    for (int k = 0; k < 31; ++k) {
        float xv = xin[k + 1];
        a0 += xv * w1[k];
        a1 += xv * w1[31 + k];
        a2 += xv * w1[62 + k];
        a3 += xv * w1[93 + k];
    }
    y1s[7 + p]        = fmaxf(a0, 0.0f);
    y1s[512 + 7 + p]  = fmaxf(a1, 0.0f);
    y1s[1024 + 7 + p] = fmaxf(a2, 0.0f);
    y1s[1536 + 7 + p] = fmaxf(a3, 0.0f);
}

__global__ void __launch_bounds__(64, 3)
wavernn_fused(const float* __restrict__ past,      // (B,2000)
              const float* __restrict__ velocity,  // (B,)
              const float* __restrict__ log_pitch, // (B,)
              const float* __restrict__ time_in,   // (B,)
              const float* __restrict__ hidden,    // (B,32)
              const float* __restrict__ w1, const float* __restrict__ b1,
              const float* __restrict__ w2, const float* __restrict__ b2,
              const float* __restrict__ w3, const float* __restrict__ b3,
              const float* __restrict__ w_ih, const float* __restrict__ w_hh,
              const float* __restrict__ b_ih, const float* __restrict__ b_hh,
              const float* __restrict__ w_proj, const float* __restrict__ b_proj,
              float* __restrict__ out, int B)
{
    __shared__ __align__(16) float xbuf[1048];
    __shared__ __align__(16) float y1s[4 * 512];
    __shared__ __align__(16) float y2s[8 * 132];
    __shared__ float rnn[20];   // [0..15]=ctx, 16=vel, 17=log_pitch, 18=time
    __shared__ float hs[32];
    __shared__ float gis[96];
    __shared__ float ghs[96];

    const int t = threadIdx.x;       // 0..63, single wave
    const int b = blockIdx.x;

    const float4* row4 = (const float4*)(past + (size_t)b * 2000);
    float4* xb4 = (float4*)xbuf;

    // ---------------- pads + small stages ----------------
    if (t < 16) { xbuf[t] = 0.0f; xbuf[1032 + t] = 0.0f; }
    if (t < 48) { int c = t / 12, k = t % 12;
                  y1s[c * 512 + (k < 7 ? k : 500 + k)] = 0.0f; }
    if (t < 56) { int c = t / 7, k = t % 7;
                  y2s[c * 132 + (k < 3 ? k : 125 + k)] = 0.0f; }
    if (t < 32) hs[t] = hidden[(size_t)b * 32 + t];
    if (t == 0) rnn[16] = velocity[b];
    if (t == 1) rnn[17] = log_pitch[b];
    if (t == 2) rnn[18] = time_in[b];

    // ---------------- conv1 chunk 0: input floats [0,1016) ----------------
#pragma unroll
    for (int j = 0; j < 4; ++j) {
        int i = t + 64 * j;
        if (i < 254) xb4[4 + i] = row4[i];       // LDS float 16+4i <- input 4i
    }
    __syncthreads();
#pragma unroll
    for (int j = 0; j < 4; ++j) {
        int p = t + 64 * j;                      // positions 0..249
        if (p < 250) conv1_pos(xbuf, y1s, w1, b1, p, p);
    }
    __syncthreads();

    // ---------------- conv1 chunk 1: input floats [984,2000) ----------------
#pragma unroll
    for (int j = 0; j < 4; ++j) {
        int i = t + 64 * j;
        if (i < 254) xb4[4 + i] = row4[246 + i]; // LDS float 16+4i <- 984+4i
    }
    __syncthreads();
#pragma unroll
    for (int j = 0; j < 4; ++j) {
        int p = 250 + t + 64 * j;                // positions 250..499
        if (p < 500) conv1_pos(xbuf, y1s, w1, b1, p, p - 246);
    }
    __syncthreads();

    // ---------------- conv2: 4->8ch, k=15, s=4; each lane: all 8 out-ch ----
#pragma unroll
    for (int jj = 0; jj < 2; ++jj) {
        int p = t + 64 * jj;
        if (p < 125) {
            float acc[8];
#pragma unroll
            for (int c = 0; c < 8; ++c) acc[c] = b2[c];
#pragma unroll
            for (int ci = 0; ci < 4; ++ci) {
                const float4* src = (const float4*)(y1s + 512 * ci);
                float xin[16];
#pragma unroll
                for (int j = 0; j < 4; ++j) {
                    float4 q = src[p + j];
                    xin[4 * j + 0] = q.x; xin[4 * j + 1] = q.y;
                    xin[4 * j + 2] = q.z; xin[4 * j + 3] = q.w;
                }
#pragma unroll
                for (int k = 0; k < 15; ++k) {
#pragma unroll
                    for (int c = 0; c < 8; ++c)
                        acc[c] += xin[k] * w2[(c * 4 + ci) * 15 + k];
                }
            }
#pragma unroll
            for (int c = 0; c < 8; ++c)
                y2s[c * 132 + 3 + p] = fmaxf(acc[c], 0.0f);
        }
    }
    __syncthreads();

    // ------- conv3: 8->16ch, k=7, s=4 + relu + mean (lanes 0..31, p=t) -----
    if (t < 32) {
        float acc[16];
#pragma unroll
        for (int c = 0; c < 16; ++c) acc[c] = 0.0f;
#pragma unroll
        for (int ci = 0; ci < 8; ++ci) {
            const float4* src = (const float4*)(y2s + 132 * ci);
            float4 q0 = src[t];
            float4 q1 = src[t + 1];
            float xin[8] = {q0.x, q0.y, q0.z, q0.w, q1.x, q1.y, q1.z, q1.w};
#pragma unroll
            for (int k = 0; k < 7; ++k) {
#pragma unroll
                for (int c = 0; c < 16; ++c)
                    acc[c] += xin[k] * w3[(c * 8 + ci) * 7 + k];
            }
        }
#pragma unroll
        for (int c = 0; c < 16; ++c) {
            float v = fmaxf(acc[c] + b3[c], 0.0f);
            v += __shfl_xor(v, 16); v += __shfl_xor(v, 8);
            v += __shfl_xor(v, 4);  v += __shfl_xor(v, 2);
            v += __shfl_xor(v, 1);
            if (t == 0) rnn[c] = v * (1.0f / 32.0f);
        }
    }
    __syncthreads();

    // ---------------- GRU gates ----------------
    {
        float rv[19];
#pragma unroll
        for (int j = 0; j < 19; ++j) rv[j] = rnn[j];

        float a = b_ih[t];
        const float* wr = w_ih + t * 19;
#pragma unroll
        for (int j = 0; j < 19; ++j) a += rv[j] * wr[j];
        gis[t] = a;
        if (t < 32) {
            float a2 = b_ih[64 + t];
            const float* wr2 = w_ih + (64 + t) * 19;
#pragma unroll
            for (int j = 0; j < 19; ++j) a2 += rv[j] * wr2[j];
            gis[64 + t] = a2;
        }

        float hv[32];
#pragma unroll
        for (int j = 0; j < 32; ++j) hv[j] = hs[j];

        float g = b_hh[t];
        const float4* wh = (const float4*)(w_hh + t * 32);
#pragma unroll
        for (int j = 0; j < 8; ++j) {
            float4 q = wh[j];
            g += hv[4 * j] * q.x + hv[4 * j + 1] * q.y +
                 hv[4 * j + 2] * q.z + hv[4 * j + 3] * q.w;
        }
        ghs[t] = g;
        if (t < 32) {
            float g2 = b_hh[64 + t];
            const float4* wh2 = (const float4*)(w_hh + (64 + t) * 32);
#pragma unroll
            for (int j = 0; j < 8; ++j) {
                float4 q = wh2[j];
                g2 += hv[4 * j] * q.x + hv[4 * j + 1] * q.y +
                      hv[4 * j + 2] * q.z + hv[4 * j + 3] * q.w;
            }
            ghs[64 + t] = g2;
        }
    }
    __syncthreads();

    // ---------------- combine + projection (lanes 0..31) ----------------
    if (t < 32) {
        const int j = t;
        float r = 1.0f / (1.0f + expf(-(gis[j] + ghs[j])));
        float z = 1.0f / (1.0f + expf(-(gis[32 + j] + ghs[32 + j])));
        float n = tanhf(gis[64 + j] + r * ghs[64 + j]);
        float nh = (1.0f - z) * n + z * hs[j];
        out[(size_t)2 * B + (size_t)b * 32 + j] = nh;   // new_hidden

        float p0 = nh * w_proj[j];
        float p1 = nh * w_proj[32 + j];
        p0 += __shfl_xor(p0, 16); p1 += __shfl_xor(p1, 16);
        p0 += __shfl_xor(p0, 8);  p1 += __shfl_xor(p1, 8);
        p0 += __shfl_xor(p0, 4);  p1 += __shfl_xor(p1, 4);
        p0 += __shfl_xor(p0, 2);  p1 += __shfl_xor(p1, 2);
        p0 += __shfl_xor(p0, 1);  p1 += __shfl_xor(p1, 1);
        if (j == 0) {
            out[b] = p0 + b_proj[0];                    // mu
            out[B + b] = expf(p1 + b_proj[1]);          // sigma
        }
    }
}

extern "C" void kernel_launch(void* const* d_in, const int* in_sizes, int n_in,
                              void* d_out, int out_size, void* d_ws, size_t ws_size,
                              hipStream_t stream)
{
    const float* past      = (const float*)d_in[0];
    const float* velocity  = (const float*)d_in[1];
    const float* log_pitch = (const float*)d_in[2];
    const float* time_in   = (const float*)d_in[3];
    const float* hidden    = (const float*)d_in[4];
    const float* w1  = (const float*)d_in[5];
    const float* b1  = (const float*)d_in[6];
    const float* w2  = (const float*)d_in[7];
    const float* b2  = (const float*)d_in[8];
    const float* w3  = (const float*)d_in[9];
    const float* b3  = (const float*)d_in[10];
    const float* wih = (const float*)d_in[11];
    const float* whh = (const float*)d_in[12];
    const float* bih = (const float*)d_in[13];
    const float* bhh = (const float*)d_in[14];
    const float* wpr = (const float*)d_in[15];
    const float* bpr = (const float*)d_in[16];

    const int B = in_sizes[0] / 2000;

    wavernn_fused<<<dim3(B), dim3(64), 0, stream>>>(
        past, velocity, log_pitch, time_in, hidden,
        w1, b1, w2, b2, w3, b3, wih, whh, bih, bhh, wpr, bpr,
        (float*)d_out, B);
}